// Round 17
// baseline (59.169 us; speedup 1.0000x reference)
//
#include <hip/hip_runtime.h>
#include <cstdint>
#include <cstddef>

// GAT layer: B=4, H=8, N=2048, Din=256, O=64
// out[b,h,i,o] = sum_j softmax_j(leaky_relu(src[i]+dst[j])) * h_[b,h,j,o] + bias[o]
//
// Tricks:
//  - row max of logits = leaky(src_i + max_j dst_j) exactly (monotonicity).
//  - exp2 SEPARABILITY, dm-shifted so every factor is provably <= 1 (f16-safe):
//      p_ij = max(u_i*E_j, v_i*F_j);  E/F tables built once per block in LDS
//      -> zero transcendentals in the inner loop.
//  - ALL intermediates f16; f32->f16 via __builtin_amdgcn_cvt_pkrtz.
//  - p row-sums via MFMA vs all-ones B frag -> same lane/reg slot as PV acc.
//  - V fragment-major: h_t[bh][j>>3][o][j&7] -> a 32-j tile is 4 KB contiguous.
//  - Barrier-free register V-pipeline in the main loop (per-step-barrier LDS
//    sharing lost twice: R9/R11). R14 XCD swizzle neutral. R15 8-deep+setprio
//    neutral -> flash is L1-delivery/stall bound at 2 waves/SIMD.
//  - R16: OCCUPANCY 2x. Block = 4 waves over 64 rows: wave = (row-group w>>1,
//    j-half w&1), m=2, 32 jc-tiles each. Grid (32,32)=1024 blocks = 4/CU =
//    4 waves/SIMD (launch_bounds(256,4), 3-deep pipe to fit 128 VGPR).
//    Per-wave V bytes halve (128 KB), total delivery unchanged; j-half
//    partials combined once in LDS at the end (exact f32 adds).

#define HEADS 8
#define DIN   256
#define HDIM  64
#define NN    2048

typedef __attribute__((ext_vector_type(8))) _Float16 f16x8;
typedef __attribute__((ext_vector_type(2))) _Float16 f16x2;
typedef __attribute__((ext_vector_type(2))) __fp16   fp16x2;
typedef __attribute__((ext_vector_type(4))) float f32x4;

union H8 { f16x8 v; f16x2 p[4]; unsigned u[4]; };
union F2U { f16x2 h; fp16x2 q; unsigned u; };

__device__ __forceinline__ f16x2 pkrtz(float a, float b) {
  F2U t; t.q = __builtin_amdgcn_cvt_pkrtz(a, b);   // v_cvt_pkrtz_f16_f32
  return t.h;
}
__device__ __forceinline__ unsigned pkrtz_u(float a, float b) {
  F2U t; t.q = __builtin_amdgcn_cvt_pkrtz(a, b);
  return t.u;
}

// ---------------- k0: merged prep: wt transpose + h f32->f16 --------------
__global__ __launch_bounds__(256) void gat_prep(const float* __restrict__ w,
                                                const float* __restrict__ h,
                                                _Float16* __restrict__ wt,
                                                _Float16* __restrict__ hc) {
  const int bid = blockIdx.x;
  if (bid < 512) {
    const int idx = bid * 256 + threadIdx.x;
    const int o  = idx & 63;
    const int k  = (idx >> 6) & 255;
    const int hd = idx >> 14;
    wt[(hd * HDIM + o) * DIN + k] = (_Float16)w[idx];
  } else {
    const int idx = (bid - 512) * 256 + threadIdx.x;
    const float* p = h + (size_t)idx * 8;
    float4 x0 = ((const float4*)p)[0];
    float4 x1 = ((const float4*)p)[1];
    H8 o;
    o.p[0] = pkrtz(x0.x, x0.y); o.p[1] = pkrtz(x0.z, x0.w);
    o.p[2] = pkrtz(x1.x, x1.y); o.p[3] = pkrtz(x1.z, x1.w);
    *(f16x8*)(hc + (size_t)idx * 8) = o.v;
  }
}

// ---------------- k1: projection + fused src/dst logit vectors ------------
// grid (HEADS, 64): head = bx, 128-row tile of B*N=8192 = by
// writes V fragment-major: h_t[bh][g = j>>3][o][j&7]  (g stride 512 elems)
__global__ __launch_bounds__(256) void gat_proj(const _Float16* __restrict__ hc,
                                                const _Float16* __restrict__ wt,
                                                const float* __restrict__ a_src,
                                                const float* __restrict__ a_dst,
                                                _Float16* __restrict__ h_t,
                                                float* __restrict__ src_s,
                                                float* __restrict__ dst_s) {
  const int head = blockIdx.x;
  const int rt   = blockIdx.y;
  const int tid  = threadIdx.x;
  const int w    = tid >> 6;
  const int lane = tid & 63;
  const int l15  = lane & 15, lg = lane >> 4;

  const int rowg = rt * 128 + w * 32;                 // global row in [0,8192)
  const _Float16* hb = hc + (size_t)rowg * DIN;
  const _Float16* wb = wt + head * (HDIM * DIN);

  f32x4 acc[2][4] = {};
#pragma unroll
  for (int kk = 0; kk < 8; ++kk) {
    const int k0 = kk * 32 + lg * 8;
    f16x8 af[2];
#pragma unroll
    for (int m = 0; m < 2; ++m)
      af[m] = *(const f16x8*)(hb + (size_t)(m * 16 + l15) * DIN + k0);
    f16x8 bfr[4];
#pragma unroll
    for (int n = 0; n < 4; ++n)
      bfr[n] = *(const f16x8*)(wb + (size_t)(n * 16 + l15) * DIN + k0);
#pragma unroll
    for (int m = 0; m < 2; ++m)
#pragma unroll
      for (int n = 0; n < 4; ++n)
        acc[m][n] = __builtin_amdgcn_mfma_f32_16x16x32_f16(af[m], bfr[n], acc[m][n], 0, 0, 0);
  }

  // fragment-major store: C regs are 4 consecutive rows(j), same col(o)
  const int b   = (rt * 128) >> 11;
  const int nl0 = ((rt * 128) & 2047) + w * 32;       // node index within batch b
  const int bh  = b * HEADS + head;
  _Float16* hb_t = h_t + (size_t)bh * (256 * 512);
#pragma unroll
  for (int m = 0; m < 2; ++m)
#pragma unroll
    for (int n = 0; n < 4; ++n) {
      uint2 pk;
      pk.x = pkrtz_u(acc[m][n][0], acc[m][n][1]);
      pk.y = pkrtz_u(acc[m][n][2], acc[m][n][3]);
      const int j0 = nl0 + m * 16 + lg * 4;           // 4 consecutive j
      const int o  = n * 16 + l15;
      *(uint2*)(hb_t + (size_t)(j0 >> 3) * 512 + o * 8 + (j0 & 7)) = pk;
    }

  // fused src/dst: src[node] = sum_o h_[node][o]*a_src[o]  (f32 acc, pre-scaled)
  const float LOG2E = 1.4426950408889634f;
  float as4[4], ad4[4];
#pragma unroll
  for (int n = 0; n < 4; ++n) {
    as4[n] = a_src[head * HDIM + n * 16 + l15];
    ad4[n] = a_dst[head * HDIM + n * 16 + l15];
  }
#pragma unroll
  for (int m = 0; m < 2; ++m)
#pragma unroll
    for (int reg = 0; reg < 4; ++reg) {
      float ps = 0.f, pd = 0.f;
#pragma unroll
      for (int n = 0; n < 4; ++n) {
        float c = acc[m][n][reg];
        ps = fmaf(c, as4[n], ps);
        pd = fmaf(c, ad4[n], pd);
      }
#pragma unroll
      for (int off = 1; off <= 8; off <<= 1) {
        ps += __shfl_xor(ps, off);
        pd += __shfl_xor(pd, off);
      }
      if (l15 == 0) {
        const int nl = nl0 + m * 16 + lg * 4 + reg;
        src_s[(size_t)bh * NN + nl] = ps * LOG2E;
        dst_s[(size_t)bh * NN + nl] = pd * LOG2E;
      }
    }
}

// ---------------- k2: flash GAT attention (4 waves/SIMD) -------------------
// grid (32, 32): i-tile(64 rows) = bx, bh = by. Wave w: row-group rg = w>>1
// (32 rows, m=2), j-half jh = w&1 (32 jc-tiles). 3-deep barrier-free register
// V-pipeline; j-half partials combined once via LDS at the end.
__global__ __launch_bounds__(256, 4) void gat_flash(const float* __restrict__ src_s,
                                                    const float* __restrict__ dst_s,
                                                    const _Float16* __restrict__ h_t,
                                                    const float* __restrict__ bias,
                                                    float* __restrict__ out) {
  const int it  = blockIdx.x;
  const int bh  = blockIdx.y;
  const int tid = threadIdx.x;
  const int w   = tid >> 6;
  const int lane = tid & 63;
  const int l15 = lane & 15, lg = lane >> 4;
  const int rg  = w >> 1;          // row-group 0/1 (32 rows each)
  const int jh  = w & 1;           // j-half 0/1 (32 jc-tiles each)

  __shared__ _Float16 Ef[NN];          // 4 KB
  __shared__ _Float16 Ff[NN];          // 4 KB
  __shared__ f32x4 Oc[2][2][4][64];    // 16 KB: jh=1 partial acc
  __shared__ f32x4 Sc[2][2][64];       // 4 KB:  jh=1 partial rowsums
  __shared__ float red[4];

  const float* dstp = dst_s + (size_t)bh * NN;
  const _Float16* vpan = h_t + (size_t)bh * (256 * 512);
  // fragment-major base for this lane: tile jc, col (n*16+l15), j-slot
  const _Float16* fb = vpan + lg * 512 + l15 * 8;
  const int jb = jh * 32;              // this wave's first jc-tile

  // 3-deep V-tile register pipeline (48 VGPR)
  f16x8 V00, V01, V02, V03, V10, V11, V12, V13, V20, V21, V22, V23;

#define LOADV(s, jc) do {                                              \
    const _Float16* fp_ = fb + (size_t)(jc) * 2048;                    \
    V##s##0 = *(const f16x8*)(fp_);                                    \
    V##s##1 = *(const f16x8*)(fp_ + 128);                              \
    V##s##2 = *(const f16x8*)(fp_ + 256);                              \
    V##s##3 = *(const f16x8*)(fp_ + 384);                              \
  } while (0)

  // issue first tiles immediately; latency hides under the prologue
  LOADV(0, jb + 0);
  LOADV(1, jb + 1);
  LOADV(2, jb + 2);

  // pass 1: this thread's 8 dst values + global max dm for this (b,h)
  float d[8];
  {
    float4 q0 = *(const float4*)(dstp + tid * 8);
    float4 q1 = *(const float4*)(dstp + tid * 8 + 4);
    d[0]=q0.x; d[1]=q0.y; d[2]=q0.z; d[3]=q0.w;
    d[4]=q1.x; d[5]=q1.y; d[6]=q1.z; d[7]=q1.w;
  }
  float dm = fmaxf(fmaxf(fmaxf(d[0],d[1]),fmaxf(d[2],d[3])),
                   fmaxf(fmaxf(d[4],d[5]),fmaxf(d[6],d[7])));
#pragma unroll
  for (int off = 32; off >= 1; off >>= 1) dm = fmaxf(dm, __shfl_xor(dm, off));
  if (lane == 0) red[w] = dm;
  __syncthreads();
  dm = fmaxf(fmaxf(red[0], red[1]), fmaxf(red[2], red[3]));

  // pass 2: E/F tables (f16, all <= 1 by dm shift)
  {
    H8 e8, f8;
#pragma unroll
    for (int k = 0; k < 4; ++k) {
      float a0 = d[2*k]   - dm;
      float a1 = d[2*k+1] - dm;
      e8.p[k] = pkrtz(__builtin_amdgcn_exp2f(a0), __builtin_amdgcn_exp2f(a1));
      f8.p[k] = pkrtz(__builtin_amdgcn_exp2f(0.2f * a0),
                      __builtin_amdgcn_exp2f(0.2f * a1));
    }
    *(f16x8*)(&Ef[tid * 8]) = e8.v;
    *(f16x8*)(&Ff[tid * 8]) = f8.v;
  }
  __syncthreads();

  // per-lane row state: A-frag row = l15 within each 16-row m-tile
  const float* srcp = src_s + (size_t)bh * NN + it * 64 + rg * 32;
  f16x2 u2[2], v2[2];
#pragma unroll
  for (int m = 0; m < 2; ++m) {
    float sv   = srcp[m * 16 + l15];
    float smax = sv + dm;
    float mi   = fmaxf(smax, 0.2f * smax);   // exact row max (log2 domain)
    float u    = __builtin_amdgcn_exp2f(smax - mi);          // <= 1
    float v    = __builtin_amdgcn_exp2f(fmaf(0.2f, smax, -mi)); // <= 1
    u2[m] = pkrtz(u, u);
    v2[m] = pkrtz(v, v);
  }

  f32x4 acc[2][4] = {};
  f32x4 accs[2]   = {};
  H8 onesU; onesU.u[0] = onesU.u[1] = onesU.u[2] = onesU.u[3] = 0x3C003C00u;
  const f16x8 ones = onesU.v;

#define STEP(s, jc) do {                                               \
    H8 eu_, fu_;                                                       \
    eu_.v = *(const f16x8*)(&Ef[(jc) * 32 + lg * 8]);                  \
    fu_.v = *(const f16x8*)(&Ff[(jc) * 32 + lg * 8]);                  \
    _Pragma("unroll") for (int m = 0; m < 2; ++m) {                    \
      H8 af_;                                                          \
      af_.p[0] = __builtin_elementwise_max(u2[m] * eu_.p[0], v2[m] * fu_.p[0]); \
      af_.p[1] = __builtin_elementwise_max(u2[m] * eu_.p[1], v2[m] * fu_.p[1]); \
      af_.p[2] = __builtin_elementwise_max(u2[m] * eu_.p[2], v2[m] * fu_.p[2]); \
      af_.p[3] = __builtin_elementwise_max(u2[m] * eu_.p[3], v2[m] * fu_.p[3]); \
      acc[m][0] = __builtin_amdgcn_mfma_f32_16x16x32_f16(af_.v, V##s##0, acc[m][0], 0, 0, 0); \
      acc[m][1] = __builtin_amdgcn_mfma_f32_16x16x32_f16(af_.v, V##s##1, acc[m][1], 0, 0, 0); \
      acc[m][2] = __builtin_amdgcn_mfma_f32_16x16x32_f16(af_.v, V##s##2, acc[m][2], 0, 0, 0); \
      acc[m][3] = __builtin_amdgcn_mfma_f32_16x16x32_f16(af_.v, V##s##3, acc[m][3], 0, 0, 0); \
      accs[m]   = __builtin_amdgcn_mfma_f32_16x16x32_f16(af_.v, ones, accs[m], 0, 0, 0);      \
    }                                                                  \
  } while (0)

  // 32 steps, 3-stage rotation; loads lead use by ~2.5 steps
#pragma unroll 1
  for (int t = 0; t < 27; t += 3) {
    STEP(0, jb + t);     LOADV(0, jb + t + 3);
    STEP(1, jb + t + 1); LOADV(1, jb + t + 4);
    STEP(2, jb + t + 2); LOADV(2, jb + t + 5);
  }
  STEP(0, jb + 27); LOADV(0, jb + 30);
  STEP(1, jb + 28); LOADV(1, jb + 31);
  STEP(2, jb + 29);
  STEP(0, jb + 30);
  STEP(1, jb + 31);

#undef LOADV
#undef STEP

  // combine j-half partials: jh=1 parks in LDS, jh=0 adds + stores (1 barrier)
  if (jh == 1) {
#pragma unroll
    for (int m = 0; m < 2; ++m) {
      Sc[rg][m][lane] = accs[m];
#pragma unroll
      for (int n = 0; n < 4; ++n) Oc[rg][m][n][lane] = acc[m][n];
    }
  }
  __syncthreads();
  if (jh == 0) {
    float bb[4];
#pragma unroll
    for (int n = 0; n < 4; ++n) bb[n] = bias[n * 16 + l15];

    float* ob = out + ((size_t)bh * NN + it * 64 + rg * 32) * HDIM;
#pragma unroll
    for (int m = 0; m < 2; ++m) {
      f32x4 st = accs[m] + Sc[rg][m][lane];
#pragma unroll
      for (int reg = 0; reg < 4; ++reg) {
        const float linv = 1.0f / st[reg];   // rowsum, same lane & reg as acc
        const int r = m * 16 + lg * 4 + reg;
#pragma unroll
        for (int n = 0; n < 4; ++n) {
          float o = acc[m][n][reg] + Oc[rg][m][n][lane][reg];
          ob[(size_t)r * HDIM + n * 16 + l15] = fmaf(o, linv, bb[n]);
        }
      }
    }
  }
}

extern "C" void kernel_launch(void* const* d_in, const int* in_sizes, int n_in,
                              void* d_out, int out_size, void* d_ws, size_t ws_size,
                              hipStream_t stream) {
  const float* h     = (const float*)d_in[0];   // [4,2048,256]
  const float* w     = (const float*)d_in[1];   // [8,256,64]
  const float* a_src = (const float*)d_in[2];   // [8,64,1]
  const float* a_dst = (const float*)d_in[3];   // [8,64,1]
  const float* bias  = (const float*)d_in[4];   // [64]
  float* out = (float*)d_out;                   // [4,8,2048,64]

  // ws layout (~8.75 MB)
  char* ws = (char*)d_ws;
  _Float16* wt  = (_Float16*)ws;                                   // 256 KB
  _Float16* h_t = (_Float16*)(ws + 262144);                        // 8 MB (V frag-major)
  float* src_s = (float*)(ws + 262144 + 8388608);                  // 256 KB
  float* dst_s = (float*)(ws + 262144 + 8388608 + 262144);         // 256 KB

  // f16 copy of h lives in the FRONT of d_out (4 MB of 16 MB): written by
  // gat_prep, read only by gat_proj, then d_out is fully rewritten by flash.
  _Float16* hcv = (_Float16*)d_out;

  hipLaunchKernelGGL(gat_prep,  dim3(1536),   dim3(256), 0, stream, w, h, wt, hcv);
  hipLaunchKernelGGL(gat_proj,  dim3(8, 64),  dim3(256), 0, stream,
                     hcv, wt, a_src, a_dst, h_t, src_s, dst_s);
  hipLaunchKernelGGL(gat_flash, dim3(32, 32), dim3(256), 0, stream,
                     src_s, dst_s, h_t, bias, out);
}

// Round 18
// 49.516 us; speedup vs baseline: 1.1949x; 1.1949x over previous
//
#include <hip/hip_runtime.h>
#include <cstdint>
#include <cstddef>

// GAT layer: B=4, H=8, N=2048, Din=256, O=64
// out[b,h,i,o] = sum_j softmax_j(leaky_relu(src[i]+dst[j])) * h_[b,h,j,o] + bias[o]
//
// Tricks:
//  - row max of logits = leaky(src_i + max_j dst_j) exactly (monotonicity).
//  - exp2 SEPARABILITY, dm-shifted so every factor is provably <= 1 (f16-safe):
//      p_ij = max(u_i*E_j, v_i*F_j);  E/F tables built once per block in LDS
//      -> zero transcendentals in the inner loop.
//  - ALL intermediates f16; f32->f16 via __builtin_amdgcn_cvt_pkrtz.
//  - p row-sums via MFMA vs all-ones B frag -> same lane/reg slot as PV acc.
//  - V fragment-major: h_t[bh][j>>3][o][j&7] -> a 32-j tile is 4 KB contiguous.
//  - flash = R10 champion (49.6us): m=2, 4 waves/block, 4-deep barrier-free
//    register V-pipeline. Failed flash alternates: R9/R11/R16 LDS-share or
//    occupancy-split (ds_read_b128 BW ~ L1 BW: no headroom + coupling),
//    R12 m=4 (1 wave/SIMD), R13 j-split, R14 XCD swizzle, R15 depth-8+setprio.
//  - R17: PROJ gets the R10 recipe — 2-deep named-register kk-pipeline
//    (was: 8x serial load->vmcnt(0)->MFMA, ~250cyc exposed latency per kk at
//    2 waves/SIMD; proj ~14us vs ~3us floor per R5's non-flash split).

#define HEADS 8
#define DIN   256
#define HDIM  64
#define NN    2048

typedef __attribute__((ext_vector_type(8))) _Float16 f16x8;
typedef __attribute__((ext_vector_type(2))) _Float16 f16x2;
typedef __attribute__((ext_vector_type(2))) __fp16   fp16x2;
typedef __attribute__((ext_vector_type(4))) float f32x4;

union H8 { f16x8 v; f16x2 p[4]; unsigned u[4]; };
union F2U { f16x2 h; fp16x2 q; unsigned u; };

__device__ __forceinline__ f16x2 pkrtz(float a, float b) {
  F2U t; t.q = __builtin_amdgcn_cvt_pkrtz(a, b);   // v_cvt_pkrtz_f16_f32
  return t.h;
}
__device__ __forceinline__ unsigned pkrtz_u(float a, float b) {
  F2U t; t.q = __builtin_amdgcn_cvt_pkrtz(a, b);
  return t.u;
}

// ---------------- k0: merged prep: wt transpose + h f32->f16 --------------
__global__ __launch_bounds__(256) void gat_prep(const float* __restrict__ w,
                                                const float* __restrict__ h,
                                                _Float16* __restrict__ wt,
                                                _Float16* __restrict__ hc) {
  const int bid = blockIdx.x;
  if (bid < 512) {
    const int idx = bid * 256 + threadIdx.x;
    const int o  = idx & 63;
    const int k  = (idx >> 6) & 255;
    const int hd = idx >> 14;
    wt[(hd * HDIM + o) * DIN + k] = (_Float16)w[idx];
  } else {
    const int idx = (bid - 512) * 256 + threadIdx.x;
    const float* p = h + (size_t)idx * 8;
    float4 x0 = ((const float4*)p)[0];
    float4 x1 = ((const float4*)p)[1];
    H8 o;
    o.p[0] = pkrtz(x0.x, x0.y); o.p[1] = pkrtz(x0.z, x0.w);
    o.p[2] = pkrtz(x1.x, x1.y); o.p[3] = pkrtz(x1.z, x1.w);
    *(f16x8*)(hc + (size_t)idx * 8) = o.v;
  }
}

// ---------------- k1: projection + fused src/dst logit vectors ------------
// grid (HEADS, 64): head = bx, 128-row tile of B*N=8192 = by
// writes V fragment-major: h_t[bh][g = j>>3][o][j&7]  (g stride 512 elems)
// R17: 2-deep named-register double buffer over the kk loop.
__global__ __launch_bounds__(256) void gat_proj(const _Float16* __restrict__ hc,
                                                const _Float16* __restrict__ wt,
                                                const float* __restrict__ a_src,
                                                const float* __restrict__ a_dst,
                                                _Float16* __restrict__ h_t,
                                                float* __restrict__ src_s,
                                                float* __restrict__ dst_s) {
  const int head = blockIdx.x;
  const int rt   = blockIdx.y;
  const int tid  = threadIdx.x;
  const int w    = tid >> 6;
  const int lane = tid & 63;
  const int l15  = lane & 15, lg = lane >> 4;

  const int rowg = rt * 128 + w * 32;                 // global row in [0,8192)
  const _Float16* hb = hc + (size_t)rowg * DIN;
  const _Float16* wb = wt + head * (HDIM * DIN);

  f32x4 acc[2][4] = {};

  // 2-deep pipeline stages: A-frags (2) + B-frags (4) each
  f16x8 Aa0, Aa1, Ab0, Ab1, Ab2, Ab3;
  f16x8 Ba0, Ba1, Bb0, Bb1, Bb2, Bb3;

#define LDP(S, kk) do {                                                \
    const int k0_ = (kk) * 32 + lg * 8;                                \
    S##a0 = *(const f16x8*)(hb + (size_t)(l15) * DIN + k0_);           \
    S##a1 = *(const f16x8*)(hb + (size_t)(16 + l15) * DIN + k0_);      \
    S##b0 = *(const f16x8*)(wb + (size_t)(l15) * DIN + k0_);           \
    S##b1 = *(const f16x8*)(wb + (size_t)(16 + l15) * DIN + k0_);      \
    S##b2 = *(const f16x8*)(wb + (size_t)(32 + l15) * DIN + k0_);      \
    S##b3 = *(const f16x8*)(wb + (size_t)(48 + l15) * DIN + k0_);      \
  } while (0)

#define MMP(S) do {                                                    \
    acc[0][0] = __builtin_amdgcn_mfma_f32_16x16x32_f16(S##a0, S##b0, acc[0][0], 0, 0, 0); \
    acc[0][1] = __builtin_amdgcn_mfma_f32_16x16x32_f16(S##a0, S##b1, acc[0][1], 0, 0, 0); \
    acc[0][2] = __builtin_amdgcn_mfma_f32_16x16x32_f16(S##a0, S##b2, acc[0][2], 0, 0, 0); \
    acc[0][3] = __builtin_amdgcn_mfma_f32_16x16x32_f16(S##a0, S##b3, acc[0][3], 0, 0, 0); \
    acc[1][0] = __builtin_amdgcn_mfma_f32_16x16x32_f16(S##a1, S##b0, acc[1][0], 0, 0, 0); \
    acc[1][1] = __builtin_amdgcn_mfma_f32_16x16x32_f16(S##a1, S##b1, acc[1][1], 0, 0, 0); \
    acc[1][2] = __builtin_amdgcn_mfma_f32_16x16x32_f16(S##a1, S##b2, acc[1][2], 0, 0, 0); \
    acc[1][3] = __builtin_amdgcn_mfma_f32_16x16x32_f16(S##a1, S##b3, acc[1][3], 0, 0, 0); \
  } while (0)

  LDP(A, 0);
#pragma unroll
  for (int kk = 0; kk < 6; kk += 2) {
    LDP(B, kk + 1);
    MMP(A);
    LDP(A, kk + 2);
    MMP(B);
  }
  LDP(B, 7);
  MMP(A);
  MMP(B);

#undef LDP
#undef MMP

  // fragment-major store: C regs are 4 consecutive rows(j), same col(o)
  const int b   = (rt * 128) >> 11;
  const int nl0 = ((rt * 128) & 2047) + w * 32;       // node index within batch b
  const int bh  = b * HEADS + head;
  _Float16* hb_t = h_t + (size_t)bh * (256 * 512);
#pragma unroll
  for (int m = 0; m < 2; ++m)
#pragma unroll
    for (int n = 0; n < 4; ++n) {
      uint2 pk;
      pk.x = pkrtz_u(acc[m][n][0], acc[m][n][1]);
      pk.y = pkrtz_u(acc[m][n][2], acc[m][n][3]);
      const int j0 = nl0 + m * 16 + lg * 4;           // 4 consecutive j
      const int o  = n * 16 + l15;
      *(uint2*)(hb_t + (size_t)(j0 >> 3) * 512 + o * 8 + (j0 & 7)) = pk;
    }

  // fused src/dst: src[node] = sum_o h_[node][o]*a_src[o]  (f32 acc, pre-scaled)
  const float LOG2E = 1.4426950408889634f;
  float as4[4], ad4[4];
#pragma unroll
  for (int n = 0; n < 4; ++n) {
    as4[n] = a_src[head * HDIM + n * 16 + l15];
    ad4[n] = a_dst[head * HDIM + n * 16 + l15];
  }
#pragma unroll
  for (int m = 0; m < 2; ++m)
#pragma unroll
    for (int reg = 0; reg < 4; ++reg) {
      float ps = 0.f, pd = 0.f;
#pragma unroll
      for (int n = 0; n < 4; ++n) {
        float c = acc[m][n][reg];
        ps = fmaf(c, as4[n], ps);
        pd = fmaf(c, ad4[n], pd);
      }
#pragma unroll
      for (int off = 1; off <= 8; off <<= 1) {
        ps += __shfl_xor(ps, off);
        pd += __shfl_xor(pd, off);
      }
      if (l15 == 0) {
        const int nl = nl0 + m * 16 + lg * 4 + reg;
        src_s[(size_t)bh * NN + nl] = ps * LOG2E;
        dst_s[(size_t)bh * NN + nl] = pd * LOG2E;
      }
    }
}

// ---------------- k2: flash GAT attention (R10 champion, verbatim) --------
// grid (16, 32): i-tile(128 rows) = bx, bh = by; 4 waves x 32 rows (2 m-tiles)
// 4-deep register pipeline over V jc-tiles; no barriers in the main loop.
__global__ __launch_bounds__(256) void gat_flash(const float* __restrict__ src_s,
                                                 const float* __restrict__ dst_s,
                                                 const _Float16* __restrict__ h_t,
                                                 const float* __restrict__ bias,
                                                 float* __restrict__ out) {
  const int it  = blockIdx.x;
  const int bh  = blockIdx.y;
  const int tid = threadIdx.x;
  const int w   = tid >> 6;
  const int lane = tid & 63;
  const int l15 = lane & 15, lg = lane >> 4;

  __shared__ _Float16 Ef[NN];    // 4 KB
  __shared__ _Float16 Ff[NN];    // 4 KB
  __shared__ float red[4];

  const float* dstp = dst_s + (size_t)bh * NN;
  const _Float16* vpan = h_t + (size_t)bh * (256 * 512);
  // fragment-major base for this lane: tile jc, col (n*16+l15), j-slot
  const _Float16* fb = vpan + lg * 512 + l15 * 8;

  // pass 1: this thread's 8 dst values + global max dm for this (b,h)
  float d[8];
  {
    float4 q0 = *(const float4*)(dstp + tid * 8);
    float4 q1 = *(const float4*)(dstp + tid * 8 + 4);
    d[0]=q0.x; d[1]=q0.y; d[2]=q0.z; d[3]=q0.w;
    d[4]=q1.x; d[5]=q1.y; d[6]=q1.z; d[7]=q1.w;
  }
  float dm = fmaxf(fmaxf(fmaxf(d[0],d[1]),fmaxf(d[2],d[3])),
                   fmaxf(fmaxf(d[4],d[5]),fmaxf(d[6],d[7])));
#pragma unroll
  for (int off = 32; off >= 1; off >>= 1) dm = fmaxf(dm, __shfl_xor(dm, off));
  if (lane == 0) red[w] = dm;
  __syncthreads();
  dm = fmaxf(fmaxf(red[0], red[1]), fmaxf(red[2], red[3]));

  // pass 2: E/F tables (f16, all <= 1 by dm shift)
  {
    H8 e8, f8;
#pragma unroll
    for (int k = 0; k < 4; ++k) {
      float a0 = d[2*k]   - dm;
      float a1 = d[2*k+1] - dm;
      e8.p[k] = pkrtz(__builtin_amdgcn_exp2f(a0), __builtin_amdgcn_exp2f(a1));
      f8.p[k] = pkrtz(__builtin_amdgcn_exp2f(0.2f * a0),
                      __builtin_amdgcn_exp2f(0.2f * a1));
    }
    *(f16x8*)(&Ef[tid * 8]) = e8.v;
    *(f16x8*)(&Ff[tid * 8]) = f8.v;
  }
  __syncthreads();

  // per-lane row state: A-frag row = l15 within each 16-row m-tile
  const float* srcp = src_s + (size_t)bh * NN + it * 128 + w * 32;
  f16x2 u2[2], v2[2];
#pragma unroll
  for (int m = 0; m < 2; ++m) {
    float sv   = srcp[m * 16 + l15];
    float smax = sv + dm;
    float mi   = fmaxf(smax, 0.2f * smax);   // exact row max (log2 domain)
    float u    = __builtin_amdgcn_exp2f(smax - mi);          // <= 1
    float v    = __builtin_amdgcn_exp2f(fmaf(0.2f, smax, -mi)); // <= 1
    u2[m] = pkrtz(u, u);
    v2[m] = pkrtz(v, v);
  }

  f32x4 acc[2][4] = {};
  f32x4 accs[2]   = {};
  H8 onesU; onesU.u[0] = onesU.u[1] = onesU.u[2] = onesU.u[3] = 0x3C003C00u;
  const f16x8 ones = onesU.v;

  // 4-deep V-tile register pipeline: 4 named sets of 4 fragments
  f16x8 V00, V01, V02, V03, V10, V11, V12, V13;
  f16x8 V20, V21, V22, V23, V30, V31, V32, V33;

#define LOADV(s, jc) do {                                              \
    const _Float16* fp_ = fb + (size_t)(jc) * 2048;                    \
    V##s##0 = *(const f16x8*)(fp_);                                    \
    V##s##1 = *(const f16x8*)(fp_ + 128);                              \
    V##s##2 = *(const f16x8*)(fp_ + 256);                              \
    V##s##3 = *(const f16x8*)(fp_ + 384);                              \
  } while (0)

#define STEP(s, jc) do {                                               \
    H8 eu_, fu_;                                                       \
    eu_.v = *(const f16x8*)(&Ef[(jc) * 32 + lg * 8]);                  \
    fu_.v = *(const f16x8*)(&Ff[(jc) * 32 + lg * 8]);                  \
    _Pragma("unroll") for (int m = 0; m < 2; ++m) {                    \
      H8 af_;                                                          \
      af_.p[0] = __builtin_elementwise_max(u2[m] * eu_.p[0], v2[m] * fu_.p[0]); \
      af_.p[1] = __builtin_elementwise_max(u2[m] * eu_.p[1], v2[m] * fu_.p[1]); \
      af_.p[2] = __builtin_elementwise_max(u2[m] * eu_.p[2], v2[m] * fu_.p[2]); \
      af_.p[3] = __builtin_elementwise_max(u2[m] * eu_.p[3], v2[m] * fu_.p[3]); \
      acc[m][0] = __builtin_amdgcn_mfma_f32_16x16x32_f16(af_.v, V##s##0, acc[m][0], 0, 0, 0); \
      acc[m][1] = __builtin_amdgcn_mfma_f32_16x16x32_f16(af_.v, V##s##1, acc[m][1], 0, 0, 0); \
      acc[m][2] = __builtin_amdgcn_mfma_f32_16x16x32_f16(af_.v, V##s##2, acc[m][2], 0, 0, 0); \
      acc[m][3] = __builtin_amdgcn_mfma_f32_16x16x32_f16(af_.v, V##s##3, acc[m][3], 0, 0, 0); \
      accs[m]   = __builtin_amdgcn_mfma_f32_16x16x32_f16(af_.v, ones, accs[m], 0, 0, 0);      \
    }                                                                  \
  } while (0)

  LOADV(0, 0);
  LOADV(1, 1);
  LOADV(2, 2);
#pragma unroll 1
  for (int t = 0; t < 60; t += 4) {
    LOADV(3, t + 3); STEP(0, t);
    LOADV(0, t + 4); STEP(1, t + 1);
    LOADV(1, t + 5); STEP(2, t + 2);
    LOADV(2, t + 6); STEP(3, t + 3);
  }
  LOADV(3, 63);
  STEP(0, 60); STEP(1, 61); STEP(2, 62); STEP(3, 63);

#undef LOADV
#undef STEP

  float bb[4];
#pragma unroll
  for (int n = 0; n < 4; ++n) bb[n] = bias[n * 16 + l15];

  float* ob = out + ((size_t)bh * NN + it * 128 + w * 32) * HDIM;
#pragma unroll
  for (int m = 0; m < 2; ++m)
#pragma unroll
    for (int reg = 0; reg < 4; ++reg) {
      const float linv = 1.0f / accs[m][reg];   // rowsum, same lane & reg as acc
      const int r = m * 16 + lg * 4 + reg;
#pragma unroll
      for (int n = 0; n < 4; ++n)
        ob[(size_t)r * HDIM + n * 16 + l15] = fmaf(acc[m][n][reg], linv, bb[n]);
    }
}

extern "C" void kernel_launch(void* const* d_in, const int* in_sizes, int n_in,
                              void* d_out, int out_size, void* d_ws, size_t ws_size,
                              hipStream_t stream) {
  const float* h     = (const float*)d_in[0];   // [4,2048,256]
  const float* w     = (const float*)d_in[1];   // [8,256,64]
  const float* a_src = (const float*)d_in[2];   // [8,64,1]
  const float* a_dst = (const float*)d_in[3];   // [8,64,1]
  const float* bias  = (const float*)d_in[4];   // [64]
  float* out = (float*)d_out;                   // [4,8,2048,64]

  // ws layout (~8.75 MB)
  char* ws = (char*)d_ws;
  _Float16* wt  = (_Float16*)ws;                                   // 256 KB
  _Float16* h_t = (_Float16*)(ws + 262144);                        // 8 MB (V frag-major)
  float* src_s = (float*)(ws + 262144 + 8388608);                  // 256 KB
  float* dst_s = (float*)(ws + 262144 + 8388608 + 262144);         // 256 KB

  // f16 copy of h lives in the FRONT of d_out (4 MB of 16 MB): written by
  // gat_prep, read only by gat_proj, then d_out is fully rewritten by flash.
  _Float16* hcv = (_Float16*)d_out;

  hipLaunchKernelGGL(gat_prep,  dim3(1536),   dim3(256), 0, stream, w, h, wt, hcv);
  hipLaunchKernelGGL(gat_proj,  dim3(8, 64),  dim3(256), 0, stream,
                     hcv, wt, a_src, a_dst, h_t, src_s, dst_s);
  hipLaunchKernelGGL(gat_flash, dim3(16, 32), dim3(256), 0, stream,
                     src_s, dst_s, h_t, bias, out);
}